// Round 1
// baseline (732.103 us; speedup 1.0000x reference)
//
#include <hip/hip_runtime.h>
#include <stdint.h>

#define NB   4096
#define DIN  1024
#define DOUT 1024
#define NL   32
#define KPW  (DIN * NL)     // 32768
#define KTOT (KPW + 64)     // 32832 (pad: 32 bias cols + 32 zero cols)
#define BKT  64
#define KITERS (KTOT / BKT) // 513
#define SPLIT_AT 257        // split-K boundary (257 + 256 iters)

typedef __attribute__((ext_vector_type(8))) short short8;          // 8 bf16 (A/B frag)
typedef __attribute__((ext_vector_type(8))) unsigned short ushort8;
typedef __attribute__((ext_vector_type(4))) float floatx4;         // C/D frag

// float -> bf16 bits, round-to-nearest-even (finite inputs only)
__device__ __forceinline__ unsigned short f2bf(float v) {
    uint32_t u = __float_as_uint(v);
    return (unsigned short)((u + 0x7FFFu + ((u >> 16) & 1u)) >> 16);
}

// async global->LDS, 16B per lane; lptr must be wave-uniform base (HW adds lane*16)
__device__ __forceinline__ void async_ld16(const void* g, void* l) {
    __builtin_amdgcn_global_load_lds(
        (const __attribute__((address_space(1))) void*)g,
        (__attribute__((address_space(3))) void*)l, 16, 0, 0);
}

// ---------------------------------------------------------------------------
// Kernel 1: per-row gating softmax + build bf16 y row:
//   y[b, i*32+l] = bf16(x[b,i] * g[b,l]) for k<32768
//   y[b, 32768+l] = bf16(g[b,l]) (l<32), zeros for 32800..32831
// ---------------------------------------------------------------------------
__global__ __launch_bounds__(256) void gate_build_y(
    const float* __restrict__ x, const float* __restrict__ gw,
    const float* __restrict__ gb, unsigned short* __restrict__ y)
{
    const int b = blockIdx.x;
    const int t = threadIdx.x;
    const float* xrow = x + (size_t)b * DIN;
    unsigned short* yrow = y + (size_t)b * KTOT;

    __shared__ float red[256];
    __shared__ float gsh[NL];

    {   // logits partial: leaf l = t&31, i-chunk c = t>>5 (8 chunks x 128)
        const int l = t & (NL - 1);
        const int c = t >> 5;
        const int i0 = c * (DIN / 8);
        float p = 0.f;
        #pragma unroll 4
        for (int i = i0; i < i0 + DIN / 8; ++i)
            p = fmaf(xrow[i], gw[i * NL + l], p);
        red[t] = p;
    }
    __syncthreads();
    if (t < NL) {
        float logit = gb[t];
        #pragma unroll
        for (int c = 0; c < 8; ++c) logit += red[t + c * NL];
        // softmax across 32 lanes (all within wave 0; xor offsets stay <32)
        float m = logit;
        for (int off = 16; off > 0; off >>= 1) m = fmaxf(m, __shfl_xor(m, off));
        float e = __expf(logit - m);
        float s = e;
        for (int off = 16; off > 0; off >>= 1) s += __shfl_xor(s, off);
        float g = e / s;
        gsh[t] = g;
        yrow[KPW + t] = f2bf(g);          // bias columns (paired with pb in pwb)
    } else if (t < 64) {
        yrow[KPW + t] = 0;                // zero padding columns
    }
    __syncthreads();

    // each thread's 8 leaf gates are fixed: l0 = (t&3)*8
    float gv[8];
    const int l0 = (t & 3) * 8;
    #pragma unroll
    for (int j = 0; j < 8; ++j) gv[j] = gsh[l0 + j];

    #pragma unroll 2
    for (int s2 = 0; s2 < 16; ++s2) {
        const int k = (s2 * 256 + t) * 8;     // 8-aligned => single i, l0..l0+7
        const float xv = xrow[k >> 5];
        ushort8 o8;
        #pragma unroll
        for (int j = 0; j < 8; ++j) o8[j] = f2bf(xv * gv[j]);
        *(ushort8*)(yrow + k) = o8;           // 16B coalesced store
    }
}

// ---------------------------------------------------------------------------
// Kernel 2: pw fp32 [1024,32768] (+ pb [1024,32]) -> bf16 pwb [1024, KTOT]
// ---------------------------------------------------------------------------
__global__ __launch_bounds__(256) void build_pwb(
    const float* __restrict__ pw, const float* __restrict__ pb,
    unsigned short* __restrict__ out)
{
    const int o = blockIdx.x;
    const int t = threadIdx.x;
    const float* src = pw + (size_t)o * KPW;
    unsigned short* dst = out + (size_t)o * KTOT;

    #pragma unroll 2
    for (int s = 0; s < 16; ++s) {
        const int k = (s * 256 + t) * 8;
        const float4 a = *(const float4*)(src + k);
        const float4 c = *(const float4*)(src + k + 4);
        ushort8 o8;
        o8[0] = f2bf(a.x); o8[1] = f2bf(a.y); o8[2] = f2bf(a.z); o8[3] = f2bf(a.w);
        o8[4] = f2bf(c.x); o8[5] = f2bf(c.y); o8[6] = f2bf(c.z); o8[7] = f2bf(c.w);
        *(ushort8*)(dst + k) = o8;
    }
    if (t < 8) {   // tail: 32 bias cols + 32 zeros
        ushort8 o8;
        #pragma unroll
        for (int j = 0; j < 8; ++j) {
            const int l = t * 8 + j;
            o8[j] = (l < NL) ? f2bf(pb[(size_t)o * NL + l]) : (unsigned short)0;
        }
        *(ushort8*)(dst + KPW + t * 8) = o8;
    }
}

// ---------------------------------------------------------------------------
// Kernel 3: C[b,o] += sum_k y[b,k]*pwb[o,k]  (m97-pattern GEMM-BT, split-K=2)
// 128x128 tile, BK=64, 4 waves (2x2), 4x4 16x16x32 bf16 MFMAs per wave
// ---------------------------------------------------------------------------
__global__ __launch_bounds__(256) void gemm_splitk(
    const unsigned short* __restrict__ A,   // y   [NB][KTOT]
    const unsigned short* __restrict__ Bm,  // pwb [DOUT][KTOT]
    float* __restrict__ C)                  // [NB][DOUT], pre-zeroed
{
    __shared__ unsigned short As[128 * BKT];
    __shared__ unsigned short Bs[128 * BKT];

    const int t    = threadIdx.x;
    const int wave = t >> 6;
    const int lane = t & 63;
    const int bn = blockIdx.x * 128;
    const int bm = blockIdx.y * 128;
    const int z  = blockIdx.z;
    const int it0 = z ? SPLIT_AT : 0;
    const int it1 = z ? KITERS : SPLIT_AT;

    const int wm = (wave >> 1) * 64;
    const int wn = (wave & 1) * 64;
    const int ml   = lane & 15;
    const int quad = lane >> 4;

    // staging map: chunk s, linear = s*256+t -> row = s*32 + t>>3, col = (t&7)*8
    const int row0 = t >> 3;
    const int uc   = (t & 7) * 8;
    const unsigned short* Ag = A  + (size_t)(bm + row0) * KTOT + uc + (size_t)it0 * BKT;
    const unsigned short* Bg = Bm + (size_t)(bn + row0) * KTOT + uc + (size_t)it0 * BKT;
    unsigned short* Al = As + wave * 512;   // + s*2048 per chunk; HW adds lane*16B
    unsigned short* Bl = Bs + wave * 512;

    floatx4 acc[4][4] = {};

    for (int it = it0; it < it1; ++it) {
        #pragma unroll
        for (int s = 0; s < 4; ++s)
            async_ld16(Ag + (size_t)(s * 32) * KTOT, Al + s * 2048);
        #pragma unroll
        for (int s = 0; s < 4; ++s)
            async_ld16(Bg + (size_t)(s * 32) * KTOT, Bl + s * 2048);
        Ag += BKT; Bg += BKT;
        __syncthreads();   // compiler emits vmcnt(0) drain before barrier

        #pragma unroll
        for (int kk = 0; kk < 2; ++kk) {
            short8 af[4], bf[4];
            #pragma unroll
            for (int im = 0; im < 4; ++im)
                af[im] = *(const short8*)(As + (wm + im * 16 + ml) * BKT + kk * 32 + quad * 8);
            #pragma unroll
            for (int in = 0; in < 4; ++in)
                bf[in] = *(const short8*)(Bs + (wn + in * 16 + ml) * BKT + kk * 32 + quad * 8);
            #pragma unroll
            for (int im = 0; im < 4; ++im)
                #pragma unroll
                for (int in = 0; in < 4; ++in)
                    acc[im][in] = __builtin_amdgcn_mfma_f32_16x16x32_bf16(
                        af[im], bf[in], acc[im][in], 0, 0, 0);
        }
        __syncthreads();   // protect LDS before next overwrite
    }

    // epilogue: C/D map col=lane&15, row=quad*4+reg (m89-verified); atomic for split-K
    #pragma unroll
    for (int im = 0; im < 4; ++im)
        #pragma unroll
        for (int in = 0; in < 4; ++in) {
            const int row = bm + wm + im * 16 + quad * 4;
            const int col = bn + wn + in * 16 + ml;
            #pragma unroll
            for (int r = 0; r < 4; ++r)
                atomicAdd(&C[(size_t)(row + r) * DOUT + col], acc[im][in][r]);
        }
}

// ---------------------------------------------------------------------------
extern "C" void kernel_launch(void* const* d_in, const int* in_sizes, int n_in,
                              void* d_out, int out_size, void* d_ws, size_t ws_size,
                              hipStream_t stream) {
    const float* x  = (const float*)d_in[0];   // [4096,1024]
    const float* gw = (const float*)d_in[1];   // [1024,32]
    const float* gb = (const float*)d_in[2];   // [32]
    const float* pw = (const float*)d_in[3];   // [1024,1024,32]
    const float* pb = (const float*)d_in[4];   // [1024,32]
    float* out = (float*)d_out;                // [4096,1024]

    unsigned short* y   = (unsigned short*)d_ws;          // 4096*KTOT bf16
    unsigned short* pwb = y + (size_t)NB * KTOT;          // 1024*KTOT bf16
    // ws use: (4096+1024)*32832*2 = 336,199,680 bytes

    hipMemsetAsync(d_out, 0, (size_t)NB * DOUT * sizeof(float), stream);
    gate_build_y<<<NB, 256, 0, stream>>>(x, gw, gb, y);
    build_pwb<<<DOUT, 256, 0, stream>>>(pw, pb, pwb);
    dim3 grid(DOUT / 128, NB / 128, 2);
    gemm_splitk<<<grid, 256, 0, stream>>>(y, pwb, out);
}

// Round 2
// 694.695 us; speedup vs baseline: 1.0538x; 1.0538x over previous
//
#include <hip/hip_runtime.h>
#include <stdint.h>

#define NB   4096
#define DIN  1024
#define DOUT 1024
#define NL   32
#define KPW  (DIN * NL)     // 32768
#define KTOT (KPW + 64)     // 32832 (pad: 32 bias cols + 32 zero cols)
#define BKT  64
#define KITERS (KTOT / BKT) // 513
#define NSPLIT 4            // split-K ways: 129+128+128+128

typedef __attribute__((ext_vector_type(8))) short short8;          // 8 bf16 (A/B frag)
typedef __attribute__((ext_vector_type(8))) unsigned short ushort8;
typedef __attribute__((ext_vector_type(4))) float floatx4;         // C/D frag

// float -> bf16 bits, round-to-nearest-even (finite inputs only)
__device__ __forceinline__ unsigned short f2bf(float v) {
    uint32_t u = __float_as_uint(v);
    return (unsigned short)((u + 0x7FFFu + ((u >> 16) & 1u)) >> 16);
}

// async global->LDS, 16B per lane; LDS dst = wave-uniform base + lane*16
__device__ __forceinline__ void async_ld16(const void* g, void* l) {
    __builtin_amdgcn_global_load_lds(
        (const __attribute__((address_space(1))) void*)g,
        (__attribute__((address_space(3))) void*)l, 16, 0, 0);
}

// ---------------------------------------------------------------------------
// Kernel 1: per-row gating softmax + build bf16 y row:
//   y[b, i*32+l] = bf16(x[b,i] * g[b,l]) for k<32768
//   y[b, 32768+l] = bf16(g[b,l]) (l<32), zeros for 32800..32831
// ---------------------------------------------------------------------------
__global__ __launch_bounds__(256) void gate_build_y(
    const float* __restrict__ x, const float* __restrict__ gw,
    const float* __restrict__ gb, unsigned short* __restrict__ y)
{
    const int b = blockIdx.x;
    const int t = threadIdx.x;
    const float* xrow = x + (size_t)b * DIN;
    unsigned short* yrow = y + (size_t)b * KTOT;

    __shared__ float red[256];
    __shared__ float gsh[NL];

    {   // logits partial: leaf l = t&31, i-chunk c = t>>5 (8 chunks x 128)
        const int l = t & (NL - 1);
        const int c = t >> 5;
        const int i0 = c * (DIN / 8);
        float p = 0.f;
        #pragma unroll 4
        for (int i = i0; i < i0 + DIN / 8; ++i)
            p = fmaf(xrow[i], gw[i * NL + l], p);
        red[t] = p;
    }
    __syncthreads();
    if (t < NL) {
        float logit = gb[t];
        #pragma unroll
        for (int c = 0; c < 8; ++c) logit += red[t + c * NL];
        float m = logit;
        for (int off = 16; off > 0; off >>= 1) m = fmaxf(m, __shfl_xor(m, off));
        float e = __expf(logit - m);
        float s = e;
        for (int off = 16; off > 0; off >>= 1) s += __shfl_xor(s, off);
        float g = e / s;
        gsh[t] = g;
        yrow[KPW + t] = f2bf(g);          // bias columns (paired with pb in pwb)
    } else if (t < 64) {
        yrow[KPW + t] = 0;                // zero padding columns
    }
    __syncthreads();

    float gv[8];
    const int l0 = (t & 3) * 8;
    #pragma unroll
    for (int j = 0; j < 8; ++j) gv[j] = gsh[l0 + j];

    #pragma unroll 2
    for (int s2 = 0; s2 < 16; ++s2) {
        const int k = (s2 * 256 + t) * 8;     // 8-aligned => single i, l0..l0+7
        const float xv = xrow[k >> 5];
        ushort8 o8;
        #pragma unroll
        for (int j = 0; j < 8; ++j) o8[j] = f2bf(xv * gv[j]);
        *(ushort8*)(yrow + k) = o8;           // 16B coalesced store
    }
}

// ---------------------------------------------------------------------------
// Kernel 2: pw fp32 [1024,32768] (+ pb [1024,32]) -> bf16 pwb [1024, KTOT]
// ---------------------------------------------------------------------------
__global__ __launch_bounds__(256) void build_pwb(
    const float* __restrict__ pw, const float* __restrict__ pb,
    unsigned short* __restrict__ out)
{
    const int o = blockIdx.x;
    const int t = threadIdx.x;
    const float* src = pw + (size_t)o * KPW;
    unsigned short* dst = out + (size_t)o * KTOT;

    #pragma unroll 2
    for (int s = 0; s < 16; ++s) {
        const int k = (s * 256 + t) * 8;
        const float4 a = *(const float4*)(src + k);
        const float4 c = *(const float4*)(src + k + 4);
        ushort8 o8;
        o8[0] = f2bf(a.x); o8[1] = f2bf(a.y); o8[2] = f2bf(a.z); o8[3] = f2bf(a.w);
        o8[4] = f2bf(c.x); o8[5] = f2bf(c.y); o8[6] = f2bf(c.z); o8[7] = f2bf(c.w);
        *(ushort8*)(dst + k) = o8;
    }
    if (t < 8) {   // tail: 32 bias cols + 32 zeros
        ushort8 o8;
        #pragma unroll
        for (int j = 0; j < 8; ++j) {
            const int l = t * 8 + j;
            o8[j] = (l < NL) ? f2bf(pb[(size_t)o * NL + l]) : (unsigned short)0;
        }
        *(ushort8*)(dst + KPW + t * 8) = o8;
    }
}

// ---------------------------------------------------------------------------
// Kernel 3: C[b,o] += sum_k y[b,k]*pwb[o,k]  (GEMM-BT, split-K=4, XOR-swizzled
// LDS). 128x128 tile, BK=64, 4 waves (2x2), 4x4 16x16x32 bf16 MFMAs per wave.
//
// LDS swizzle: row r (128 B = exactly one bank period) stores data 16B-chunk
// d at slot d ^ (r&7). global_load_lds pins lane->slot, so the *global*
// source address is permuted on the write side; reads apply the same XOR.
// Kills the 16-way bank conflict of the naive layout (1.0e8 conflict cycles
// in round 1 = 36% of all CU cycles).
// ---------------------------------------------------------------------------
__global__ __launch_bounds__(256) void gemm_splitk(
    const unsigned short* __restrict__ A,   // y   [NB][KTOT]
    const unsigned short* __restrict__ Bm,  // pwb [DOUT][KTOT]
    float* __restrict__ C)                  // [NB][DOUT], pre-zeroed
{
    __shared__ unsigned short As[128 * BKT];
    __shared__ unsigned short Bs[128 * BKT];

    const int t    = threadIdx.x;
    const int wave = t >> 6;
    const int lane = t & 63;

    // XCD-aware decode: xcd = id%8 (HW round-robin heuristic). The 8 bn-blocks
    // sharing one (bm,z) A-panel get IDs congruent mod 8 -> same XCD L2.
    const int id  = blockIdx.x;
    const int xcd = id & 7;
    const int s_  = id >> 3;               // 0..127
    const int bn  = (s_ & 7) * 128;
    const int idx = xcd * 16 + (s_ >> 3);  // 0..127
    const int bm  = (idx & 31) * 128;
    const int z   = idx >> 5;              // 0..3
    const int it0 = z * 128 + (z ? 1 : 0); // splits: 129+128+128+128
    const int it1 = (z + 1) * 128 + 1;

    const int wm = (wave >> 1) * 64;
    const int wn = (wave & 1) * 64;
    const int ml   = lane & 15;
    const int quad = lane >> 4;
    const int xorm = ml & 7;               // read-side swizzle key (row&7)

    // staging: linear chunk = s*256+t -> row = s*32 + (t>>3), stored slot t&7.
    // Swizzle: slot c holds data chunk c ^ (row&7); row&7 = (t>>3)&7.
    const int row0 = t >> 3;
    const int uc   = (((t & 7) ^ ((t >> 3) & 7)) * 8);
    const unsigned short* Ag = A  + (size_t)(bm + row0) * KTOT + uc + (size_t)it0 * BKT;
    const unsigned short* Bg = Bm + (size_t)(bn + row0) * KTOT + uc + (size_t)it0 * BKT;
    unsigned short* Al = As + wave * 512;   // + s*2048 per chunk; HW adds lane*16B
    unsigned short* Bl = Bs + wave * 512;

    floatx4 acc[4][4] = {};

    for (int it = it0; it < it1; ++it) {
        #pragma unroll
        for (int s = 0; s < 4; ++s)
            async_ld16(Ag + (size_t)(s * 32) * KTOT, Al + s * 2048);
        #pragma unroll
        for (int s = 0; s < 4; ++s)
            async_ld16(Bg + (size_t)(s * 32) * KTOT, Bl + s * 2048);
        Ag += BKT; Bg += BKT;
        __syncthreads();

        #pragma unroll
        for (int kk = 0; kk < 2; ++kk) {
            const int swzA = ((kk * 4 + quad) ^ xorm) * 8;  // 16B-chunk XOR, in elems
            short8 af[4], bf[4];
            #pragma unroll
            for (int im = 0; im < 4; ++im)
                af[im] = *(const short8*)(As + (wm + im * 16 + ml) * BKT + swzA);
            #pragma unroll
            for (int in = 0; in < 4; ++in)
                bf[in] = *(const short8*)(Bs + (wn + in * 16 + ml) * BKT + swzA);
            #pragma unroll
            for (int im = 0; im < 4; ++im)
                #pragma unroll
                for (int in = 0; in < 4; ++in)
                    acc[im][in] = __builtin_amdgcn_mfma_f32_16x16x32_bf16(
                        af[im], bf[in], acc[im][in], 0, 0, 0);
        }
        __syncthreads();
    }

    // epilogue: C/D map col=lane&15, row=quad*4+reg (m89-verified); atomic for split-K
    #pragma unroll
    for (int im = 0; im < 4; ++im)
        #pragma unroll
        for (int in = 0; in < 4; ++in) {
            const int row = bm + wm + im * 16 + quad * 4;
            const int col = bn + wn + in * 16 + ml;
            #pragma unroll
            for (int r = 0; r < 4; ++r)
                atomicAdd(&C[(size_t)(row + r) * DOUT + col], acc[im][in][r]);
        }
}

// ---------------------------------------------------------------------------
extern "C" void kernel_launch(void* const* d_in, const int* in_sizes, int n_in,
                              void* d_out, int out_size, void* d_ws, size_t ws_size,
                              hipStream_t stream) {
    const float* x  = (const float*)d_in[0];   // [4096,1024]
    const float* gw = (const float*)d_in[1];   // [1024,32]
    const float* gb = (const float*)d_in[2];   // [32]
    const float* pw = (const float*)d_in[3];   // [1024,1024,32]
    const float* pb = (const float*)d_in[4];   // [1024,32]
    float* out = (float*)d_out;                // [4096,1024]

    unsigned short* y   = (unsigned short*)d_ws;          // 4096*KTOT bf16
    unsigned short* pwb = y + (size_t)NB * KTOT;          // 1024*KTOT bf16
    // ws use: (4096+1024)*32832*2 = 336,199,680 bytes

    hipMemsetAsync(d_out, 0, (size_t)NB * DOUT * sizeof(float), stream);
    gate_build_y<<<NB, 256, 0, stream>>>(x, gw, gb, y);
    build_pwb<<<DOUT, 256, 0, stream>>>(pw, pb, pwb);
    gemm_splitk<<<(DOUT / 128) * (NB / 128) * NSPLIT, 256, 0, stream>>>(y, pwb, out);
}

// Round 3
// 552.486 us; speedup vs baseline: 1.3251x; 1.2574x over previous
//
#include <hip/hip_runtime.h>
#include <stdint.h>

#define NB   4096
#define DIN  1024
#define DOUT 1024
#define NL   32
#define KPW  (DIN * NL)     // 32768
#define KTOT (KPW + 64)     // 32832 (pad: 32 bias cols + 32 zero cols)
#define BKT  64
#define KITERS (KTOT / BKT) // 513
#define NSPLIT 4            // split-K ways: 129+128+128+128

typedef __attribute__((ext_vector_type(8))) short short8;          // 8 bf16 (A/B frag)
typedef __attribute__((ext_vector_type(8))) unsigned short ushort8;
typedef __attribute__((ext_vector_type(4))) float floatx4;         // C/D frag

// float -> bf16 bits, round-to-nearest-even (finite inputs only)
__device__ __forceinline__ unsigned short f2bf(float v) {
    uint32_t u = __float_as_uint(v);
    return (unsigned short)((u + 0x7FFFu + ((u >> 16) & 1u)) >> 16);
}

// two floats -> packed bf16x2 (RNE), low half = a: 2x(bfe+add) + v_perm_b32
__device__ __forceinline__ uint32_t f2bf2(float a, float b) {
    uint32_t ua = __float_as_uint(a), ub = __float_as_uint(b);
    ua += 0x7FFFu + ((ua >> 16) & 1u);
    ub += 0x7FFFu + ((ub >> 16) & 1u);
    return __builtin_amdgcn_perm(ub, ua, 0x07060302u);  // {ub_hi16, ua_hi16}
}

// async global->LDS, 16B per lane; LDS dst = wave-uniform base + lane*16
__device__ __forceinline__ void async_ld16(const void* g, void* l) {
    __builtin_amdgcn_global_load_lds(
        (const __attribute__((address_space(1))) void*)g,
        (__attribute__((address_space(3))) void*)l, 16, 0, 0);
}

// ---------------------------------------------------------------------------
// Kernel 1: gating softmax -> g [NB][NL] fp32. One wave per row (4 rows/block).
// ---------------------------------------------------------------------------
__global__ __launch_bounds__(256) void gate_kernel(
    const float* __restrict__ x, const float* __restrict__ gw,
    const float* __restrict__ gb, float* __restrict__ g)
{
    const int wave = threadIdx.x >> 6;
    const int lane = threadIdx.x & 63;
    const int b = blockIdx.x * 4 + wave;
    const int l = lane & 31;
    const int c = lane >> 5;              // half-wave handles 512 of 1024 i's
    const float* xrow = x + (size_t)b * DIN;

    float p0 = 0.f, p1 = 0.f, p2 = 0.f, p3 = 0.f;
    const int i0 = c * 512;
    #pragma unroll 2
    for (int j = 0; j < 512; j += 4) {
        const int i = i0 + j;
        p0 = fmaf(xrow[i + 0], gw[(i + 0) * NL + l], p0);
        p1 = fmaf(xrow[i + 1], gw[(i + 1) * NL + l], p1);
        p2 = fmaf(xrow[i + 2], gw[(i + 2) * NL + l], p2);
        p3 = fmaf(xrow[i + 3], gw[(i + 3) * NL + l], p3);
    }
    float p = (p0 + p1) + (p2 + p3);
    p += __shfl_xor(p, 32);               // combine the two i-halves
    const float logit = p + gb[l];
    float m = logit;
    for (int off = 16; off > 0; off >>= 1) m = fmaxf(m, __shfl_xor(m, off));
    const float e = __expf(logit - m);
    float s = e;
    for (int off = 16; off > 0; off >>= 1) s += __shfl_xor(s, off);
    if (lane < NL) g[(size_t)b * NL + l] = e / s;
}

// ---------------------------------------------------------------------------
// Kernel 2: pw fp32 [1024,32768] (+ pb [1024,32]) -> bf16 pwb [1024, KTOT]
// ---------------------------------------------------------------------------
__global__ __launch_bounds__(256) void build_pwb(
    const float* __restrict__ pw, const float* __restrict__ pb,
    unsigned short* __restrict__ out)
{
    const int o = blockIdx.x;
    const int t = threadIdx.x;
    const float* src = pw + (size_t)o * KPW;
    unsigned short* dst = out + (size_t)o * KTOT;

    #pragma unroll 2
    for (int s = 0; s < 16; ++s) {
        const int k = (s * 256 + t) * 8;
        const float4 a = *(const float4*)(src + k);
        const float4 c = *(const float4*)(src + k + 4);
        ushort8 o8;
        o8[0] = f2bf(a.x); o8[1] = f2bf(a.y); o8[2] = f2bf(a.z); o8[3] = f2bf(a.w);
        o8[4] = f2bf(c.x); o8[5] = f2bf(c.y); o8[6] = f2bf(c.z); o8[7] = f2bf(c.w);
        *(ushort8*)(dst + k) = o8;
    }
    if (t < 8) {   // tail: 32 bias cols + 32 zeros
        ushort8 o8;
        #pragma unroll
        for (int j = 0; j < 8; ++j) {
            const int l = t * 8 + j;
            o8[j] = (l < NL) ? f2bf(pb[(size_t)o * NL + l]) : (unsigned short)0;
        }
        *(ushort8*)(dst + KPW + t * 8) = o8;
    }
}

// ---------------------------------------------------------------------------
// Kernel 3: C[b,o] += sum_k y[b,k]*pwb[o,k] with y built ON THE FLY in LDS:
//   y[b, i*32+l] = bf16(x[b,i]*g[b,l]);  bias iter (i=1024) uses x==1.
// Removes the 269MB y write + 269MB re-read of rounds 1-2.
// 128x128 tile, BK=64, split-K=4, XOR-swizzled LDS (r2: conflicts 1e8->0).
// A-build: thread t owns row r=t>>1, leaves lh=(t&1)*16..+15 (16 g regs),
// writes 4x ds_write_b128 per iter into slot (chunk ^ (r&7)) — 2-way banks.
// ---------------------------------------------------------------------------
__global__ __launch_bounds__(256, 4) void gemm_splitk(
    const float* __restrict__ X,            // x [NB][DIN] fp32
    const float* __restrict__ G,            // g [NB][NL]  fp32
    const unsigned short* __restrict__ Bw,  // pwb [DOUT][KTOT] bf16
    float* __restrict__ C)                  // [NB][DOUT], pre-zeroed
{
    __shared__ unsigned short As[128 * BKT];
    __shared__ unsigned short Bs[128 * BKT];

    const int t    = threadIdx.x;
    const int wave = t >> 6;
    const int lane = t & 63;

    // XCD-aware decode: 8 bn-blocks sharing one (bm,z) A-panel -> same XCD L2
    const int id  = blockIdx.x;
    const int xcd = id & 7;
    const int s_  = id >> 3;               // 0..127
    const int bn  = (s_ & 7) * 128;
    const int idx = xcd * 16 + (s_ >> 3);  // 0..127
    const int bm  = (idx & 31) * 128;
    const int z   = idx >> 5;              // 0..3
    const int it0 = z * 128 + (z ? 1 : 0); // splits: 129+128+128+128
    const int it1 = (z + 1) * 128 + 1;

    const int wm = (wave >> 1) * 64;
    const int wn = (wave & 1) * 64;
    const int ml   = lane & 15;
    const int quad = lane >> 4;
    const int xorm = ml & 7;

    // B staging via async DMA (swizzled source, as r2)
    const int row0 = t >> 3;
    const int uc   = (((t & 7) ^ ((t >> 3) & 7)) * 8);
    const unsigned short* Bg = Bw + (size_t)(bn + row0) * KTOT + uc + (size_t)it0 * BKT;
    unsigned short* Bl = Bs + wave * 512;   // + s*2048 per chunk; HW adds lane*16B

    // A on-the-fly build
    const int r   = t >> 1;                 // row 0..127
    const int lh  = (t & 1) * 16;           // leaf base 0 or 16
    const int rx  = r & 7;
    const float* xp = X + (size_t)(bm + r) * DIN;
    unsigned short* Aw = As + r * BKT;
    float gq[16];
    {
        const float* gp = G + (size_t)(bm + r) * NL + lh;
        #pragma unroll
        for (int q = 0; q < 4; ++q) {
            const float4 v = *(const float4*)(gp + q * 4);
            gq[q * 4 + 0] = v.x; gq[q * 4 + 1] = v.y;
            gq[q * 4 + 2] = v.z; gq[q * 4 + 3] = v.w;
        }
    }

    floatx4 acc[4][4] = {};
    float2 xv = *(const float2*)(xp + min(it0 * 2, DIN - 2));

    for (int it = it0; it < it1; ++it) {
        // 1) B tile DMA (overlaps the VALU A-build below)
        #pragma unroll
        for (int s = 0; s < 4; ++s)
            async_ld16(Bg + (size_t)(s * 32) * KTOT, Bl + s * 2048);
        Bg += BKT;

        // 2) bias fixup (uniform branch; only it==512 hits it)
        const bool inb = (it * 2) < DIN;
        const float xa = inb ? xv.x : 1.0f;   // i=1024: y-col = g (pairs with pb)
        const float xb = inb ? xv.y : 0.0f;   // i=1025: zero pad
        // 3) prefetch next x (clamped; drained by the same pre-barrier wait)
        xv = *(const float2*)(xp + min((it + 1) * 2, DIN - 2));

        // 4) build 32 bf16 of As: rows fixed, chunks c = ii*4 + (t&1)*2 + j
        #pragma unroll
        for (int ii = 0; ii < 2; ++ii) {
            const float xs = ii ? xb : xa;
            #pragma unroll
            for (int j = 0; j < 2; ++j) {
                uint4 v;
                v.x = f2bf2(xs * gq[j * 8 + 0], xs * gq[j * 8 + 1]);
                v.y = f2bf2(xs * gq[j * 8 + 2], xs * gq[j * 8 + 3]);
                v.z = f2bf2(xs * gq[j * 8 + 4], xs * gq[j * 8 + 5]);
                v.w = f2bf2(xs * gq[j * 8 + 6], xs * gq[j * 8 + 7]);
                const int c = ii * 4 + (t & 1) * 2 + j;
                *(uint4*)(Aw + ((c ^ rx) * 8)) = v;
            }
        }
        __syncthreads();

        #pragma unroll
        for (int kk = 0; kk < 2; ++kk) {
            const int swz = ((kk * 4 + quad) ^ xorm) * 8;
            short8 af[4], bf[4];
            #pragma unroll
            for (int im = 0; im < 4; ++im)
                af[im] = *(const short8*)(As + (wm + im * 16 + ml) * BKT + swz);
            #pragma unroll
            for (int in = 0; in < 4; ++in)
                bf[in] = *(const short8*)(Bs + (wn + in * 16 + ml) * BKT + swz);
            #pragma unroll
            for (int im = 0; im < 4; ++im)
                #pragma unroll
                for (int in = 0; in < 4; ++in)
                    acc[im][in] = __builtin_amdgcn_mfma_f32_16x16x32_bf16(
                        af[im], bf[in], acc[im][in], 0, 0, 0);
        }
        __syncthreads();
    }

    // epilogue: C/D map col=lane&15, row=quad*4+reg (m89-verified); atomic for split-K
    #pragma unroll
    for (int im = 0; im < 4; ++im)
        #pragma unroll
        for (int in = 0; in < 4; ++in) {
            const int row = bm + wm + im * 16 + quad * 4;
            const int col = bn + wn + in * 16 + ml;
            #pragma unroll
            for (int rr = 0; rr < 4; ++rr)
                atomicAdd(&C[(size_t)(row + rr) * DOUT + col], acc[im][in][rr]);
        }
}

// ---------------------------------------------------------------------------
extern "C" void kernel_launch(void* const* d_in, const int* in_sizes, int n_in,
                              void* d_out, int out_size, void* d_ws, size_t ws_size,
                              hipStream_t stream) {
    const float* x  = (const float*)d_in[0];   // [4096,1024]
    const float* gw = (const float*)d_in[1];   // [1024,32]
    const float* gb = (const float*)d_in[2];   // [32]
    const float* pw = (const float*)d_in[3];   // [1024,1024,32]
    const float* pb = (const float*)d_in[4];   // [1024,32]
    float* out = (float*)d_out;                // [4096,1024]

    float* g            = (float*)d_ws;                               // 512 KB
    unsigned short* pwb = (unsigned short*)((char*)d_ws + (1 << 20)); // 67.2 MB
    // ws use: 1 MB + 1024*32832*2 = ~68.3 MB

    hipMemsetAsync(d_out, 0, (size_t)NB * DOUT * sizeof(float), stream);
    gate_kernel<<<NB / 4, 256, 0, stream>>>(x, gw, gb, g);
    build_pwb<<<DOUT, 256, 0, stream>>>(pw, pb, pwb);
    gemm_splitk<<<(DOUT / 128) * (NB / 128) * NSPLIT, 256, 0, stream>>>(x, g, pwb, out);
}